// Round 3
// baseline (38863.452 us; speedup 1.0000x reference)
//
#include <hip/hip_runtime.h>
#include <hip/hip_cooperative_groups.h>

namespace cg = cooperative_groups;

// ---------------------------------------------------------------------------
// LanguageModel: embed -> LSTM(1024) x2 -> last-step logits(32000) -> softmax
// B=64, S=512, E=512, H=1024, G=4H=4096, V=32000
//
// Round 2: round-1 persistent-cooperative structure + fix for the x4 batch
// offset bug (wave w must read batch rows w*16+r0.., not r0..).
//  - 256 blocks x 256 thr (1 block/CU). Block b owns h-cols [4b,4b+4) ->
//    16 gate-cols (i,f,g,o interleaved). Wh slice = 32 KB resident in VGPRs.
//  - c-state register-resident; h double-buffered global; grid.sync per step.
// ---------------------------------------------------------------------------

#define BB 64
#define SS 512
#define EE 512
#define HH 1024
#define GG 4096
#define VV 32000

using bf16x8 = __attribute__((ext_vector_type(8))) __bf16;
using f32x4  = __attribute__((ext_vector_type(4))) float;

__device__ __forceinline__ unsigned short f2bf(float f) {
    unsigned u = __float_as_uint(f);
    unsigned r = u + 0x7FFFu + ((u >> 16) & 1u);   // RNE
    return (unsigned short)(r >> 16);
}
__device__ __forceinline__ float bf2f(unsigned short u) {
    return __uint_as_float(((unsigned)u) << 16);
}
__device__ __forceinline__ float sigm(float x) {
    return 1.0f / (1.0f + expf(-x));
}

// Packed-B layout: elem(nt, kt, lane, j) = B[kt*32 + (lane>>4)*8 + j][nt*16 + (lane&15)]
__global__ void pack_b(const float* __restrict__ B, unsigned short* __restrict__ out,
                       int KT, int N) {
    int bid = blockIdx.x;          // = nt*KT + kt
    int lane = threadIdx.x;
    int nt = bid / KT, kt = bid % KT;
    int k = kt * 32 + ((lane >> 4) << 3);
    int n = nt * 16 + (lane & 15);
    size_t base = ((size_t)bid * 64 + lane) * 8;
    #pragma unroll
    for (int j = 0; j < 8; ++j)
        out[base + j] = f2bf(B[(size_t)(k + j) * N + n]);
}

// Wh pack for the persistent kernel: per block b (0..255), 16 cols ordered
// [i0..i3, f0..f3, g0..g3, o0..o3] where hcols = 4b..4b+3.
__global__ void pack_wh(const float* __restrict__ Wh, unsigned short* __restrict__ out) {
    int bid = blockIdx.x;          // = b*32 + kt
    int lane = threadIdx.x;
    int b = bid >> 5, kt = bid & 31;
    int c = lane & 15;
    int gcol = (c >> 2) * HH + 4 * b + (c & 3);
    int k = kt * 32 + ((lane >> 4) << 3);
    size_t base = ((size_t)bid * 64 + lane) * 8;
    #pragma unroll
    for (int j = 0; j < 8; ++j)
        out[base + j] = f2bf(Wh[(size_t)(k + j) * GG + gcol]);
}

// Embedding gather written directly in packed-A form (M=32768 rows, K=512).
__global__ void embed_pack(const int* __restrict__ x, const float* __restrict__ tab,
                           unsigned short* __restrict__ out) {
    int bid = blockIdx.x;          // = mt*16 + kt  (KT=16)
    int lane = threadIdx.x;
    int mt = bid >> 4, kt = bid & 15;
    int m = mt * 16 + (lane & 15);
    int idx = x[m];
    int kb = kt * 32 + ((lane >> 4) << 3);
    size_t base = ((size_t)bid * 64 + lane) * 8;
    const float* src = tab + (size_t)idx * EE + kb;
    #pragma unroll
    for (int j = 0; j < 8; ++j)
        out[base + j] = f2bf(src[j]);
}

// C = A@B + bias.  MODE 0: float row-major (logits).
//                  MODE 1: bf16 x4s layout out[((s*GG + col)*64 + batch)], row = batch*SS+s.
template<int MODE>
__global__ __launch_bounds__(256) void gemm_bias(
    const unsigned short* __restrict__ Ap, const unsigned short* __restrict__ Bp,
    const float* __restrict__ bias, void* __restrict__ Cout, int N, int KT) {
    const int tid = threadIdx.x, lane = tid & 63, w = tid >> 6;
    const int ntg = blockIdx.x * 4 + w;
    const int m0t = blockIdx.y * 4;
    const bf16x8* Av = reinterpret_cast<const bf16x8*>(Ap);
    const bf16x8* Bv = reinterpret_cast<const bf16x8*>(Bp);
    f32x4 acc[4] = {{0.f,0.f,0.f,0.f},{0.f,0.f,0.f,0.f},{0.f,0.f,0.f,0.f},{0.f,0.f,0.f,0.f}};
    for (int kt = 0; kt < KT; ++kt) {
        bf16x8 b = Bv[((size_t)ntg * KT + kt) * 64 + lane];
        #pragma unroll
        for (int mt = 0; mt < 4; ++mt) {
            bf16x8 a = Av[((size_t)(m0t + mt) * KT + kt) * 64 + lane];
            acc[mt] = __builtin_amdgcn_mfma_f32_16x16x32_bf16(a, b, acc[mt], 0, 0, 0);
        }
    }
    const int col = ntg * 16 + (lane & 15);
    const int rq = (lane >> 4) << 2;
    const float bb = bias[col];
    #pragma unroll
    for (int mt = 0; mt < 4; ++mt)
        #pragma unroll
        for (int i = 0; i < 4; ++i) {
            int row = (m0t + mt) * 16 + rq + i;
            float v = acc[mt][i] + bb;
            if (MODE == 0) {
                ((float*)Cout)[(size_t)row * N + col] = v;
            } else {
                int batch = row >> 9, s = row & 511;
                ((unsigned short*)Cout)[((size_t)s * GG + col) * 64 + batch] = f2bf(v);
            }
        }
}

// Persistent LSTM layer. Grid 256 x 256 (cooperative). Block b: h-cols 4b..4b+3.
__global__ __launch_bounds__(256, 1) void lstm_layer(
    const unsigned short* __restrict__ x4s, const unsigned short* __restrict__ whp,
    unsigned short* __restrict__ hb0, unsigned short* __restrict__ hb1,
    unsigned short* __restrict__ h1A) {
    cg::grid_group grid = cg::this_grid();
    __shared__ float gx[4][16][16];   // [wave][gate-col][batch-row]
    const int tid = threadIdx.x, lane = tid & 63, w = tid >> 6;
    const int b = blockIdx.x;
    const bf16x8* whv = reinterpret_cast<const bf16x8*>(whp);

    // Wh slice resident in registers: 32 bf16x8 = 128 VGPRs.
    bf16x8 Breg[32];
    #pragma unroll
    for (int kt = 0; kt < 32; ++kt)
        Breg[kt] = whv[((size_t)b * 32 + kt) * 64 + lane];

    // elementwise mapping: lane -> (r, j): batch row = 16w + r, hcol = 4b + j
    const int r = lane >> 2, j = lane & 3;
    const int row = w * 16 + r;
    // packed-A index for the h write (M=64, K=1024)
    const int kt_h = b >> 3, sub = (b >> 1) & 3, jl = 4 * (b & 1) + j;
    const size_t hidx = (((size_t)w * 32 + kt_h) * 64 + sub * 16 + r) * 8 + jl;

    float c = 0.f;
    hb0[hidx] = 0;                    // zero own slice of h_0
    grid.sync();

    const int cc = lane & 15;                                 // acc col
    const int gcol = (cc >> 2) * HH + 4 * b + (cc & 3);       // natural gate col
    const int r0 = (lane >> 4) << 2;                          // acc row base (within wave tile)

    #pragma unroll 1
    for (int t = 0; t < SS; ++t) {
        const bf16x8* hv = reinterpret_cast<const bf16x8*>((t & 1) ? hb1 : hb0);
        unsigned short* hout = (t & 1) ? hb0 : hb1;
        bf16x8 Areg[32];
        #pragma unroll
        for (int kt = 0; kt < 32; ++kt)
            Areg[kt] = hv[((size_t)w * 32 + kt) * 64 + lane];
        f32x4 acc = {0.f, 0.f, 0.f, 0.f};
        #pragma unroll
        for (int kt = 0; kt < 32; ++kt)
            acc = __builtin_amdgcn_mfma_f32_16x16x32_bf16(Areg[kt], Breg[kt], acc, 0, 0, 0);
        // add x4: global batch rows for this wave's C tile are w*16 + r0 + i
        // (round-1 bug: offset was missing the w*16 term)
        const ushort4 xv = *reinterpret_cast<const ushort4*>(
            x4s + ((size_t)t * GG + gcol) * 64 + w * 16 + r0);
        gx[w][cc][r0 + 0] = acc[0] + bf2f(xv.x);
        gx[w][cc][r0 + 1] = acc[1] + bf2f(xv.y);
        gx[w][cc][r0 + 2] = acc[2] + bf2f(xv.z);
        gx[w][cc][r0 + 3] = acc[3] + bf2f(xv.w);
        __syncthreads();
        float gi = gx[w][j][r], gf = gx[w][4 + j][r];
        float gg = gx[w][8 + j][r], go = gx[w][12 + j][r];
        float cn = sigm(gf) * c + sigm(gi) * tanhf(gg);
        c = cn;
        float h = sigm(go) * tanhf(cn);
        unsigned short hbv = f2bf(h);
        hout[hidx] = hbv;
        if (h1A) {
            int m = row * SS + t;
            h1A[(((size_t)(m >> 4) * 32 + kt_h) * 64 + sub * 16 + (m & 15)) * 8 + jl] = hbv;
        }
        grid.sync();
    }
}

__global__ __launch_bounds__(256) void softmax_rows(const float* __restrict__ logits,
                                                    float* __restrict__ out) {
    __shared__ float red[256];
    int rr = blockIdx.x, tid = threadIdx.x;
    const float* L = logits + (size_t)rr * VV;
    float m = -1e30f;
    for (int i = tid; i < VV; i += 256) m = fmaxf(m, L[i]);
    red[tid] = m; __syncthreads();
    for (int s = 128; s > 0; s >>= 1) { if (tid < s) red[tid] = fmaxf(red[tid], red[tid + s]); __syncthreads(); }
    m = red[0]; __syncthreads();
    float sum = 0.f;
    for (int i = tid; i < VV; i += 256) sum += expf(L[i] - m);
    red[tid] = sum; __syncthreads();
    for (int s = 128; s > 0; s >>= 1) { if (tid < s) red[tid] += red[tid + s]; __syncthreads(); }
    float inv = 1.f / red[0];
    for (int i = tid; i < VV; i += 256) out[(size_t)rr * VV + i] = expf(L[i] - m) * inv;
}

extern "C" void kernel_launch(void* const* d_in, const int* in_sizes, int n_in,
                              void* d_out, int out_size, void* d_ws, size_t ws_size,
                              hipStream_t stream) {
    const int*   x    = (const int*)  d_in[0];
    const float* tab  = (const float*)d_in[1];
    const float* Wx0  = (const float*)d_in[2];
    const float* Wh0  = (const float*)d_in[3];
    const float* b0   = (const float*)d_in[4];
    const float* Wx1  = (const float*)d_in[5];
    const float* Wh1  = (const float*)d_in[6];
    const float* b1   = (const float*)d_in[7];
    const float* Wout = (const float*)d_in[8];
    const float* bout = (const float*)d_in[9];
    float* out = (float*)d_out;

    // ---- workspace layout (ushort units); all segments 16B-aligned ----
    unsigned short* ws    = (unsigned short*)d_ws;
    unsigned short* embA  = ws;                    // 16,777,216
    unsigned short* wx0p  = embA  + 16777216;      //  2,097,152
    unsigned short* wh0p  = wx0p  + 2097152;       //  4,194,304
    unsigned short* wx1p  = wh0p  + 4194304;       //  4,194,304
    unsigned short* wh1p  = wx1p  + 4194304;       //  4,194,304
    unsigned short* woutp = wh1p  + 4194304;       // 32,768,000
    unsigned short* x4s   = woutp + 32768000;      // 134,217,728 (reused by both layers)
    unsigned short* h1A   = x4s   + 134217728;     // 33,554,432
    unsigned short* hb0   = h1A   + 33554432;      // 65,536
    unsigned short* hb1   = hb0   + 65536;         // 65,536
    float* logits = (float*)(hb1 + 65536);         // 2,048,000 f32
    // total ~472 MB

    // ---- weight packing ----
    pack_b <<<256 * 16, 64, 0, stream>>>(Wx0, wx0p, 16, GG);
    pack_wh<<<256 * 32, 64, 0, stream>>>(Wh0, wh0p);
    pack_b <<<256 * 32, 64, 0, stream>>>(Wx1, wx1p, 32, GG);
    pack_wh<<<256 * 32, 64, 0, stream>>>(Wh1, wh1p);
    pack_b <<<2000 * 32, 64, 0, stream>>>(Wout, woutp, 32, VV);

    // ---- embedding + layer-0 input projection ----
    embed_pack<<<32768, 64, 0, stream>>>(x, tab, embA);
    gemm_bias<1><<<dim3(GG / 64, 32768 / 64), 256, 0, stream>>>(embA, wx0p, b0, x4s, GG, EE / 32);

    // ---- layer 0 recurrence (persistent cooperative) ----
    {
        const unsigned short* a0 = x4s; const unsigned short* a1 = wh0p;
        unsigned short *a2 = hb0, *a3 = hb1, *a4 = h1A;
        void* args[] = {&a0, &a1, &a2, &a3, &a4};
        hipLaunchCooperativeKernel((const void*)lstm_layer, dim3(256), dim3(256),
                                   args, 0, stream);
    }

    // ---- layer-1 input projection + recurrence ----
    gemm_bias<1><<<dim3(GG / 64, 32768 / 64), 256, 0, stream>>>(h1A, wx1p, b1, x4s, GG, HH / 32);
    {
        const unsigned short* a0 = x4s; const unsigned short* a1 = wh1p;
        unsigned short *a2 = hb0, *a3 = hb1, *a4 = nullptr;
        void* args[] = {&a0, &a1, &a2, &a3, &a4};
        hipLaunchCooperativeKernel((const void*)lstm_layer, dim3(256), dim3(256),
                                   args, 0, stream);
    }
    // t=511 writes hb0

    // ---- logits (last timestep) + softmax ----
    gemm_bias<0><<<dim3(VV / 64, 1), 256, 0, stream>>>(hb0, woutp, bout, logits, VV, HH / 32);
    softmax_rows<<<64, 256, 0, stream>>>(logits, out);
}

// Round 4
// 29401.328 us; speedup vs baseline: 1.3218x; 1.3218x over previous
//
#include <hip/hip_runtime.h>

// ---------------------------------------------------------------------------
// LanguageModel: embed -> LSTM(1024) x2 -> last-step logits(32000) -> softmax
// B=64, S=512, E=512, H=1024, G=4H=4096, V=32000
//
// Round 3: persistent cooperative recurrence, with round-2's two stalls fixed:
//  - Wh slice staged in LDS (32 KB/block, once) -> ds_read_b128 per step.
//    (round 2: compiler sank the 128-VGPR Breg array back into the loop,
//     VGPR_Count=92, per-step Wh re-fetch, 34.6 us/step.)
//  - custom monotonic atomic grid barrier instead of cg::grid.sync()
//    (release atomicAdd + relaxed spin + __threadfence on both sides).
//  - h0 + barrier counters zeroed in a pre-kernel; per-layer h buffers.
// ---------------------------------------------------------------------------

#define BB 64
#define SS 512
#define EE 512
#define HH 1024
#define GG 4096
#define VV 32000

using bf16x8 = __attribute__((ext_vector_type(8))) __bf16;
using f32x4  = __attribute__((ext_vector_type(4))) float;

__device__ __forceinline__ unsigned short f2bf(float f) {
    unsigned u = __float_as_uint(f);
    unsigned r = u + 0x7FFFu + ((u >> 16) & 1u);   // RNE
    return (unsigned short)(r >> 16);
}
__device__ __forceinline__ float bf2f(unsigned short u) {
    return __uint_as_float(((unsigned)u) << 16);
}
__device__ __forceinline__ float sigm(float x) {
    return 1.0f / (1.0f + expf(-x));
}

// Packed-B layout: elem(nt, kt, lane, j) = B[kt*32 + (lane>>4)*8 + j][nt*16 + (lane&15)]
__global__ void pack_b(const float* __restrict__ B, unsigned short* __restrict__ out,
                       int KT, int N) {
    int bid = blockIdx.x;          // = nt*KT + kt
    int lane = threadIdx.x;
    int nt = bid / KT, kt = bid % KT;
    int k = kt * 32 + ((lane >> 4) << 3);
    int n = nt * 16 + (lane & 15);
    size_t base = ((size_t)bid * 64 + lane) * 8;
    #pragma unroll
    for (int j = 0; j < 8; ++j)
        out[base + j] = f2bf(B[(size_t)(k + j) * N + n]);
}

// Wh pack: per block b (0..255), 16 cols ordered [i0..3,f0..3,g0..3,o0..3],
// hcols = 4b..4b+3.
__global__ void pack_wh(const float* __restrict__ Wh, unsigned short* __restrict__ out) {
    int bid = blockIdx.x;          // = b*32 + kt
    int lane = threadIdx.x;
    int b = bid >> 5, kt = bid & 31;
    int c = lane & 15;
    int gcol = (c >> 2) * HH + 4 * b + (c & 3);
    int k = kt * 32 + ((lane >> 4) << 3);
    size_t base = ((size_t)bid * 64 + lane) * 8;
    #pragma unroll
    for (int j = 0; j < 8; ++j)
        out[base + j] = f2bf(Wh[(size_t)(k + j) * GG + gcol]);
}

// Embedding gather written directly in packed-A form (M=32768 rows, K=512).
__global__ void embed_pack(const int* __restrict__ x, const float* __restrict__ tab,
                           unsigned short* __restrict__ out) {
    int bid = blockIdx.x;          // = mt*16 + kt  (KT=16)
    int lane = threadIdx.x;
    int mt = bid >> 4, kt = bid & 15;
    int m = mt * 16 + (lane & 15);
    int idx = x[m];
    int kb = kt * 32 + ((lane >> 4) << 3);
    size_t base = ((size_t)bid * 64 + lane) * 8;
    const float* src = tab + (size_t)idx * EE + kb;
    #pragma unroll
    for (int j = 0; j < 8; ++j)
        out[base + j] = f2bf(src[j]);
}

// C = A@B + bias.  MODE 0: float row-major (logits).
//                  MODE 1: bf16 x4s layout out[((s*GG + col)*64 + batch)], row = batch*SS+s.
template<int MODE>
__global__ __launch_bounds__(256) void gemm_bias(
    const unsigned short* __restrict__ Ap, const unsigned short* __restrict__ Bp,
    const float* __restrict__ bias, void* __restrict__ Cout, int N, int KT) {
    const int tid = threadIdx.x, lane = tid & 63, w = tid >> 6;
    const int ntg = blockIdx.x * 4 + w;
    const int m0t = blockIdx.y * 4;
    const bf16x8* Av = reinterpret_cast<const bf16x8*>(Ap);
    const bf16x8* Bv = reinterpret_cast<const bf16x8*>(Bp);
    f32x4 acc[4] = {{0.f,0.f,0.f,0.f},{0.f,0.f,0.f,0.f},{0.f,0.f,0.f,0.f},{0.f,0.f,0.f,0.f}};
    for (int kt = 0; kt < KT; ++kt) {
        bf16x8 b = Bv[((size_t)ntg * KT + kt) * 64 + lane];
        #pragma unroll
        for (int mt = 0; mt < 4; ++mt) {
            bf16x8 a = Av[((size_t)(m0t + mt) * KT + kt) * 64 + lane];
            acc[mt] = __builtin_amdgcn_mfma_f32_16x16x32_bf16(a, b, acc[mt], 0, 0, 0);
        }
    }
    const int col = ntg * 16 + (lane & 15);
    const int rq = (lane >> 4) << 2;
    const float bb = bias[col];
    #pragma unroll
    for (int mt = 0; mt < 4; ++mt)
        #pragma unroll
        for (int i = 0; i < 4; ++i) {
            int row = (m0t + mt) * 16 + rq + i;
            float v = acc[mt][i] + bb;
            if (MODE == 0) {
                ((float*)Cout)[(size_t)row * N + col] = v;
            } else {
                int batch = row >> 9, s = row & 511;
                ((unsigned short*)Cout)[((size_t)s * GG + col) * 64 + batch] = f2bf(v);
            }
        }
}

// Zero h0 for both layers + the two barrier counters.
__global__ void zero_init(unsigned short* __restrict__ h0a,
                          unsigned short* __restrict__ h0b,
                          unsigned int* __restrict__ ctrs) {
    int i = blockIdx.x * 256 + threadIdx.x;      // grid 64 x 256
    for (int k = i; k < BB * HH; k += 64 * 256) { h0a[k] = 0; h0b[k] = 0; }
    if (i < 8) ctrs[i] = 0;
}

// Persistent LSTM layer. Grid 256 x 256 (cooperative). Block b: h-cols 4b..4b+3.
__global__ __launch_bounds__(256, 1) void lstm_layer(
    const unsigned short* __restrict__ x4s, const unsigned short* __restrict__ whp,
    unsigned short* __restrict__ hb0, unsigned short* __restrict__ hb1,
    unsigned short* __restrict__ h1A, unsigned int* __restrict__ ctr) {
    __shared__ float gx[4][16][16];                 // [wave][gate-col][batch-row]
    __shared__ unsigned short Blds[32 * 64 * 8];    // 32 KB Wh slice
    const int tid = threadIdx.x, lane = tid & 63, w = tid >> 6;
    const int b = blockIdx.x;

    // ---- stage this block's Wh slice into LDS (once) ----
    {
        const float4* src = reinterpret_cast<const float4*>(whp) + (size_t)b * 2048;
        float4* dst = reinterpret_cast<float4*>(Blds);
        #pragma unroll
        for (int i = 0; i < 8; ++i)
            dst[i * 256 + tid] = src[i * 256 + tid];
    }
    __syncthreads();
    const bf16x8* Bl = reinterpret_cast<const bf16x8*>(Blds);

    // elementwise mapping: lane -> (r, j): batch row = 16w + r, hcol = 4b + j
    const int r = lane >> 2, j = lane & 3;
    const int row = w * 16 + r;
    // packed-A index for the h write (M=64, K=1024)
    const int kt_h = b >> 3, sub = (b >> 1) & 3, jl = 4 * (b & 1) + j;
    const size_t hidx = (((size_t)w * 32 + kt_h) * 64 + sub * 16 + r) * 8 + jl;

    const int cc = lane & 15;                                 // acc col
    const int gcol = (cc >> 2) * HH + 4 * b + (cc & 3);       // natural gate col
    const int r0 = (lane >> 4) << 2;                          // acc row base

    float c = 0.f;

    #pragma unroll 1
    for (int t = 0; t < SS; ++t) {
        const bf16x8* hv = reinterpret_cast<const bf16x8*>((t & 1) ? hb1 : hb0);
        unsigned short* hout = (t & 1) ? hb0 : hb1;

        // load this wave's 16 batch rows of h (32 independent dwordx4)
        bf16x8 Areg[32];
        #pragma unroll
        for (int kt = 0; kt < 32; ++kt)
            Areg[kt] = hv[((size_t)w * 32 + kt) * 64 + lane];

        f32x4 acc = {0.f, 0.f, 0.f, 0.f};
        #pragma unroll
        for (int kt = 0; kt < 32; ++kt)
            acc = __builtin_amdgcn_mfma_f32_16x16x32_bf16(Areg[kt], Bl[kt * 64 + lane], acc, 0, 0, 0);

        // add x4 for this wave's batch rows (w*16 + r0 + i)
        const ushort4 xv = *reinterpret_cast<const ushort4*>(
            x4s + ((size_t)t * GG + gcol) * 64 + w * 16 + r0);
        gx[w][cc][r0 + 0] = acc[0] + bf2f(xv.x);
        gx[w][cc][r0 + 1] = acc[1] + bf2f(xv.y);
        gx[w][cc][r0 + 2] = acc[2] + bf2f(xv.z);
        gx[w][cc][r0 + 3] = acc[3] + bf2f(xv.w);
        __syncthreads();

        float gi = gx[w][j][r], gf = gx[w][4 + j][r];
        float gg = gx[w][8 + j][r], go = gx[w][12 + j][r];
        float cn = sigm(gf) * c + sigm(gi) * tanhf(gg);
        c = cn;
        float h = sigm(go) * tanhf(cn);
        unsigned short hbv = f2bf(h);
        hout[hidx] = hbv;
        if (h1A) {
            int m = row * SS + t;
            h1A[(((size_t)(m >> 4) * 32 + kt_h) * 64 + sub * 16 + (m & 15)) * 8 + jl] = hbv;
        }

        // ---- grid barrier (monotonic counter, device scope) ----
        __syncthreads();               // all block stores drained (vmcnt before s_barrier)
        if (tid == 0) {
            __threadfence();           // release: push block's h writes past L2
            __hip_atomic_fetch_add(ctr, 1u, __ATOMIC_RELEASE, __HIP_MEMORY_SCOPE_AGENT);
            const unsigned target = (unsigned)(t + 1) * 256u;
            while (__hip_atomic_load(ctr, __ATOMIC_RELAXED, __HIP_MEMORY_SCOPE_AGENT) < target)
                __builtin_amdgcn_s_sleep(2);
            __threadfence();           // acquire: invalidate stale L1/L2 before next reads
        }
        __syncthreads();
    }
}

__global__ __launch_bounds__(256) void softmax_rows(const float* __restrict__ logits,
                                                    float* __restrict__ out) {
    __shared__ float red[256];
    int rr = blockIdx.x, tid = threadIdx.x;
    const float* L = logits + (size_t)rr * VV;
    float m = -1e30f;
    for (int i = tid; i < VV; i += 256) m = fmaxf(m, L[i]);
    red[tid] = m; __syncthreads();
    for (int s = 128; s > 0; s >>= 1) { if (tid < s) red[tid] = fmaxf(red[tid], red[tid + s]); __syncthreads(); }
    m = red[0]; __syncthreads();
    float sum = 0.f;
    for (int i = tid; i < VV; i += 256) sum += expf(L[i] - m);
    red[tid] = sum; __syncthreads();
    for (int s = 128; s > 0; s >>= 1) { if (tid < s) red[tid] += red[tid + s]; __syncthreads(); }
    float inv = 1.f / red[0];
    for (int i = tid; i < VV; i += 256) out[(size_t)rr * VV + i] = expf(L[i] - m) * inv;
}

extern "C" void kernel_launch(void* const* d_in, const int* in_sizes, int n_in,
                              void* d_out, int out_size, void* d_ws, size_t ws_size,
                              hipStream_t stream) {
    const int*   x    = (const int*)  d_in[0];
    const float* tab  = (const float*)d_in[1];
    const float* Wx0  = (const float*)d_in[2];
    const float* Wh0  = (const float*)d_in[3];
    const float* b0   = (const float*)d_in[4];
    const float* Wx1  = (const float*)d_in[5];
    const float* Wh1  = (const float*)d_in[6];
    const float* b1   = (const float*)d_in[7];
    const float* Wout = (const float*)d_in[8];
    const float* bout = (const float*)d_in[9];
    float* out = (float*)d_out;

    // ---- workspace layout (ushort units); all segments 16B-aligned ----
    unsigned short* ws    = (unsigned short*)d_ws;
    unsigned short* embA  = ws;                    // 16,777,216
    unsigned short* wx0p  = embA  + 16777216;      //  2,097,152
    unsigned short* wh0p  = wx0p  + 2097152;       //  4,194,304
    unsigned short* wx1p  = wh0p  + 4194304;       //  4,194,304
    unsigned short* wh1p  = wx1p  + 4194304;       //  4,194,304
    unsigned short* woutp = wh1p  + 4194304;       // 32,768,000
    unsigned short* x4s   = woutp + 32768000;      // 134,217,728 (reused by both layers)
    unsigned short* h1A   = x4s   + 134217728;     // 33,554,432
    unsigned short* hb0   = h1A   + 33554432;      // 65,536  (layer 0)
    unsigned short* hb1   = hb0   + 65536;         // 65,536
    unsigned short* hb2   = hb1   + 65536;         // 65,536  (layer 1)
    unsigned short* hb3   = hb2   + 65536;         // 65,536
    float* logits = (float*)(hb3 + 65536);         // 2,048,000 f32
    unsigned int* ctrs = (unsigned int*)(logits + 2048000);  // 8 u32 (ctr0, ctr1)
    // total ~472 MB

    // ---- weight packing ----
    pack_b <<<256 * 16, 64, 0, stream>>>(Wx0, wx0p, 16, GG);
    pack_wh<<<256 * 32, 64, 0, stream>>>(Wh0, wh0p);
    pack_b <<<256 * 32, 64, 0, stream>>>(Wx1, wx1p, 32, GG);
    pack_wh<<<256 * 32, 64, 0, stream>>>(Wh1, wh1p);
    pack_b <<<2000 * 32, 64, 0, stream>>>(Wout, woutp, 32, VV);

    // ---- h0 + counters init ----
    zero_init<<<64, 256, 0, stream>>>(hb0, hb2, ctrs);

    // ---- embedding + layer-0 input projection ----
    embed_pack<<<32768, 64, 0, stream>>>(x, tab, embA);
    gemm_bias<1><<<dim3(GG / 64, 32768 / 64), 256, 0, stream>>>(embA, wx0p, b0, x4s, GG, EE / 32);

    // ---- layer 0 recurrence (persistent cooperative) ----
    {
        const unsigned short* a0 = x4s; const unsigned short* a1 = wh0p;
        unsigned short *a2 = hb0, *a3 = hb1, *a4 = h1A;
        unsigned int* a5 = ctrs;
        void* args[] = {&a0, &a1, &a2, &a3, &a4, &a5};
        hipLaunchCooperativeKernel((const void*)lstm_layer, dim3(256), dim3(256),
                                   args, 0, stream);
    }

    // ---- layer-1 input projection + recurrence ----
    gemm_bias<1><<<dim3(GG / 64, 32768 / 64), 256, 0, stream>>>(h1A, wx1p, b1, x4s, GG, HH / 32);
    {
        const unsigned short* a0 = x4s; const unsigned short* a1 = wh1p;
        unsigned short *a2 = hb2, *a3 = hb3, *a4 = nullptr;
        unsigned int* a5 = ctrs + 4;
        void* args[] = {&a0, &a1, &a2, &a3, &a4, &a5};
        hipLaunchCooperativeKernel((const void*)lstm_layer, dim3(256), dim3(256),
                                   args, 0, stream);
    }
    // t=511 (odd) writes hb2

    // ---- logits (last timestep) + softmax ----
    gemm_bias<0><<<dim3(VV / 64, 1), 256, 0, stream>>>(hb2, woutp, bout, logits, VV, HH / 32);
    softmax_rows<<<64, 256, 0, stream>>>(logits, out);
}

// Round 5
// 10665.528 us; speedup vs baseline: 3.6438x; 2.7567x over previous
//
#include <hip/hip_runtime.h>

// ---------------------------------------------------------------------------
// LanguageModel: embed -> LSTM(1024) x2 -> last-step logits(32000) -> softmax
// B=64, S=512, E=512, H=1024, G=4H=4096, V=32000
//
// Round 4: fence-free persistent recurrence.
//  - Coherence: h + flags via agent-scope RELAXED atomics (sc1: bypass L1/L2,
//    coherent at Infinity Cache). NO __threadfence / wbl2 / inv in the loop.
//  - Barrier: distributed per-block flags (64B padded), 128-block domains
//    (batch halves are independent), relaxed polls + s_sleep.
//  - Partition: block = (colgroup g in [0,128), batch-half hf in {0,1}).
//    Block owns 8 contiguous h-cols x 32 batch rows; Wh slice 64 KB in LDS.
//    All hout/h1A 64B lines written by exactly one block (no false sharing).
// ---------------------------------------------------------------------------

#define BB 64
#define SS 512
#define EE 512
#define HH 1024
#define GG 4096
#define VV 32000

using bf16x8 = __attribute__((ext_vector_type(8))) __bf16;
using f32x4  = __attribute__((ext_vector_type(4))) float;

__device__ __forceinline__ unsigned short f2bf(float f) {
    unsigned u = __float_as_uint(f);
    unsigned r = u + 0x7FFFu + ((u >> 16) & 1u);   // RNE
    return (unsigned short)(r >> 16);
}
__device__ __forceinline__ float bf2f(unsigned short u) {
    return __uint_as_float(((unsigned)u) << 16);
}
__device__ __forceinline__ float sigm(float x) {
    return 1.0f / (1.0f + expf(-x));
}
// 16B fragment load via two agent-scope relaxed atomics (sc1 -> coherent at IF).
__device__ __forceinline__ bf16x8 ld_frag_coh(const unsigned long long* p) {
    union { unsigned long long u[2]; bf16x8 v; } x;
    x.u[0] = __hip_atomic_load(p,     __ATOMIC_RELAXED, __HIP_MEMORY_SCOPE_AGENT);
    x.u[1] = __hip_atomic_load(p + 1, __ATOMIC_RELAXED, __HIP_MEMORY_SCOPE_AGENT);
    return x.v;
}

// Packed-B layout: elem(nt, kt, lane, j) = B[kt*32 + (lane>>4)*8 + j][nt*16 + (lane&15)]
__global__ void pack_b(const float* __restrict__ B, unsigned short* __restrict__ out,
                       int KT, int N) {
    int bid = blockIdx.x;          // = nt*KT + kt
    int lane = threadIdx.x;
    int nt = bid / KT, kt = bid % KT;
    int k = kt * 32 + ((lane >> 4) << 3);
    int n = nt * 16 + (lane & 15);
    size_t base = ((size_t)bid * 64 + lane) * 8;
    #pragma unroll
    for (int j = 0; j < 8; ++j)
        out[base + j] = f2bf(B[(size_t)(k + j) * N + n]);
}

// Wh pack for round-4 partition: colgroup g in [0,128) owns h-cols 8g..8g+7
// -> 32 gate-cols ordered n = q*8+cj (q=gate, cj=col offset), as 2 n-tiles.
// Frag id f = (g*2 + nt)*32 + kt.
__global__ void pack_wh(const float* __restrict__ Wh, unsigned short* __restrict__ out) {
    int f = blockIdx.x;            // (g*2 + nt)*32 + kt ; grid 8192
    int lane = threadIdx.x;
    int kt = f & 31, nt = (f >> 5) & 1, g = f >> 6;
    int nloc = lane & 15;
    int q = nt * 2 + (nloc >> 3), cj = nloc & 7;
    int gcol = q * HH + 8 * g + cj;
    int k = kt * 32 + ((lane >> 4) << 3);
    size_t base = ((size_t)f * 64 + lane) * 8;
    #pragma unroll
    for (int j = 0; j < 8; ++j)
        out[base + j] = f2bf(Wh[(size_t)(k + j) * GG + gcol]);
}

// Embedding gather written directly in packed-A form (M=32768 rows, K=512).
__global__ void embed_pack(const int* __restrict__ x, const float* __restrict__ tab,
                           unsigned short* __restrict__ out) {
    int bid = blockIdx.x;          // = mt*16 + kt  (KT=16)
    int lane = threadIdx.x;
    int mt = bid >> 4, kt = bid & 15;
    int m = mt * 16 + (lane & 15);
    int idx = x[m];
    int kb = kt * 32 + ((lane >> 4) << 3);
    size_t base = ((size_t)bid * 64 + lane) * 8;
    const float* src = tab + (size_t)idx * EE + kb;
    #pragma unroll
    for (int j = 0; j < 8; ++j)
        out[base + j] = f2bf(src[j]);
}

// C = A@B + bias.  MODE 0: float row-major (logits).
//                  MODE 1: bf16 x4s layout out[((s*GG + col)*64 + batch)], row = batch*SS+s.
template<int MODE>
__global__ __launch_bounds__(256) void gemm_bias(
    const unsigned short* __restrict__ Ap, const unsigned short* __restrict__ Bp,
    const float* __restrict__ bias, void* __restrict__ Cout, int N, int KT) {
    const int tid = threadIdx.x, lane = tid & 63, w = tid >> 6;
    const int ntg = blockIdx.x * 4 + w;
    const int m0t = blockIdx.y * 4;
    const bf16x8* Av = reinterpret_cast<const bf16x8*>(Ap);
    const bf16x8* Bv = reinterpret_cast<const bf16x8*>(Bp);
    f32x4 acc[4] = {{0.f,0.f,0.f,0.f},{0.f,0.f,0.f,0.f},{0.f,0.f,0.f,0.f},{0.f,0.f,0.f,0.f}};
    for (int kt = 0; kt < KT; ++kt) {
        bf16x8 b = Bv[((size_t)ntg * KT + kt) * 64 + lane];
        #pragma unroll
        for (int mt = 0; mt < 4; ++mt) {
            bf16x8 a = Av[((size_t)(m0t + mt) * KT + kt) * 64 + lane];
            acc[mt] = __builtin_amdgcn_mfma_f32_16x16x32_bf16(a, b, acc[mt], 0, 0, 0);
        }
    }
    const int col = ntg * 16 + (lane & 15);
    const int rq = (lane >> 4) << 2;
    const float bb = bias[col];
    #pragma unroll
    for (int mt = 0; mt < 4; ++mt)
        #pragma unroll
        for (int i = 0; i < 4; ++i) {
            int row = (m0t + mt) * 16 + rq + i;
            float v = acc[mt][i] + bb;
            if (MODE == 0) {
                ((float*)Cout)[(size_t)row * N + col] = v;
            } else {
                int batch = row >> 9, s = row & 511;
                ((unsigned short*)Cout)[((size_t)s * GG + col) * 64 + batch] = f2bf(v);
            }
        }
}

// Zero h0 for both layers + all barrier flags.
__global__ void zero_init(unsigned short* __restrict__ h0a,
                          unsigned short* __restrict__ h0b,
                          unsigned int* __restrict__ flags) {
    int i = blockIdx.x * 256 + threadIdx.x;      // grid 64 x 256
    for (int k = i; k < BB * HH; k += 64 * 256) { h0a[k] = 0; h0b[k] = 0; }
    for (int k = i; k < 8192; k += 64 * 256) flags[k] = 0;
}

// Persistent LSTM layer. Grid 256 x 256 (cooperative).
// Block b: g = b>>1 (h-cols 8g..8g+7 -> 32 gate-cols), hf = b&1 (batch rows 32hf..+31).
__global__ __launch_bounds__(256, 1) void lstm_layer(
    const unsigned short* __restrict__ x4s, const unsigned short* __restrict__ whp,
    unsigned short* __restrict__ hbA, unsigned short* __restrict__ hbB,
    unsigned short* __restrict__ h1A, unsigned int* __restrict__ flagsL) {
    __shared__ float gx[32][36];                            // [n][block-row], padded
    __shared__ __align__(16) unsigned short hlds[32][8];    // gathered h chunks
    __shared__ __align__(16) unsigned short Blds[128 * 64 * 8];  // 64 KB Wh slice
    const int tid = threadIdx.x, lane = tid & 63, w = tid >> 6;
    const int g = blockIdx.x >> 1, hf = blockIdx.x & 1;
    unsigned int* flags = flagsL + hf * 2048;               // 128 flags x 16 u32 pad

    // ---- stage this colgroup's Wh slice (64 KB) into LDS, once ----
    {
        const uint4* src = reinterpret_cast<const uint4*>(whp) + (size_t)g * 4096;
        uint4* dst = reinterpret_cast<uint4*>(Blds);
        #pragma unroll
        for (int i = 0; i < 16; ++i)
            dst[i * 256 + tid] = src[i * 256 + tid];
    }
    __syncthreads();
    const bf16x8* Bl = reinterpret_cast<const bf16x8*>(Blds);

    const int msub = w & 1, nsub = w >> 1;
    const int nloc = lane & 15;
    const int q = nsub * 2 + (nloc >> 3), cj = nloc & 7;    // gate, col-offset
    const int gq = q * HH + 8 * g + cj;                     // global gate col
    const int rbase = msub * 16 + ((lane >> 4) << 2);       // block-local row base
    const size_t afrag_base = ((size_t)(2 * hf + msub) * 32) * 64 + lane;

    // elementwise thread mapping
    const int row_l = tid >> 3, cj2 = tid & 7;
    float c = 0.f;

    #pragma unroll 1
    for (int t = 0; t < SS; ++t) {
        const unsigned long long* hv =
            reinterpret_cast<const unsigned long long*>((t & 1) ? hbB : hbA);
        unsigned short* hout = (t & 1) ? hbA : hbB;

        f32x4 acc = {0.f, 0.f, 0.f, 0.f};
        #pragma unroll
        for (int kt = 0; kt < 32; ++kt) {
            bf16x8 a = ld_frag_coh(hv + (afrag_base + (size_t)kt * 64) * 2);
            acc = __builtin_amdgcn_mfma_f32_16x16x32_bf16(
                a, Bl[(nsub * 32 + kt) * 64 + lane], acc, 0, 0, 0);
        }

        // add x4 for rows 32hf + rbase + i
        const ushort4 xv = *reinterpret_cast<const ushort4*>(
            x4s + ((size_t)t * GG + gq) * 64 + 32 * hf + rbase);
        const int n = nsub * 16 + nloc;
        gx[n][rbase + 0] = acc[0] + bf2f(xv.x);
        gx[n][rbase + 1] = acc[1] + bf2f(xv.y);
        gx[n][rbase + 2] = acc[2] + bf2f(xv.z);
        gx[n][rbase + 3] = acc[3] + bf2f(xv.w);
        __syncthreads();

        // elementwise: thread -> (row_l, cj2); n = q*8 + cj
        float gi = gx[0 * 8 + cj2][row_l], gf = gx[1 * 8 + cj2][row_l];
        float gg = gx[2 * 8 + cj2][row_l], go = gx[3 * 8 + cj2][row_l];
        float cn = sigm(gf) * c + sigm(gi) * tanhf(gg);
        c = cn;
        hlds[row_l][cj2] = f2bf(sigm(go) * tanhf(cn));
        __syncthreads();

        // gather 16B chunks; one full line per 4 rows, all owned by this block
        if (tid < 32) {
            union { uint4 v; unsigned long long u[2]; } cv;
            cv.v = *reinterpret_cast<const uint4*>(&hlds[tid][0]);
            const int m = 32 * hf + tid;
            unsigned long long* dst = reinterpret_cast<unsigned long long*>(
                hout + (((size_t)(m >> 4) * 32 + (g >> 2)) * 64 + (g & 3) * 16 + (m & 15)) * 8);
            __hip_atomic_store(dst,     cv.u[0], __ATOMIC_RELAXED, __HIP_MEMORY_SCOPE_AGENT);
            __hip_atomic_store(dst + 1, cv.u[1], __ATOMIC_RELAXED, __HIP_MEMORY_SCOPE_AGENT);
            if (h1A) {   // plain store; each 64B line filled by this block over 4 steps
                const size_t mg = (size_t)m * SS + t;
                *reinterpret_cast<uint4*>(
                    h1A + (((mg >> 4) * 32 + (size_t)(g >> 2)) * 64 + (g & 3) * 16 + (mg & 15)) * 8) = cv.v;
            }
        }

        // ---- release: drain own stores; no cache ops ----
        asm volatile("s_waitcnt vmcnt(0)" ::: "memory");
        __syncthreads();
        if (tid == 0)
            __hip_atomic_store(&flags[g * 16], (unsigned)(t + 1),
                               __ATOMIC_RELAXED, __HIP_MEMORY_SCOPE_AGENT);
        if (tid < 128) {
            while (__hip_atomic_load(&flags[tid * 16], __ATOMIC_RELAXED,
                                     __HIP_MEMORY_SCOPE_AGENT) < (unsigned)(t + 1))
                __builtin_amdgcn_s_sleep(1);
        }
        __syncthreads();
    }
}

__global__ __launch_bounds__(256) void softmax_rows(const float* __restrict__ logits,
                                                    float* __restrict__ out) {
    __shared__ float red[256];
    int rr = blockIdx.x, tid = threadIdx.x;
    const float* L = logits + (size_t)rr * VV;
    float m = -1e30f;
    for (int i = tid; i < VV; i += 256) m = fmaxf(m, L[i]);
    red[tid] = m; __syncthreads();
    for (int s = 128; s > 0; s >>= 1) { if (tid < s) red[tid] = fmaxf(red[tid], red[tid + s]); __syncthreads(); }
    m = red[0]; __syncthreads();
    float sum = 0.f;
    for (int i = tid; i < VV; i += 256) sum += expf(L[i] - m);
    red[tid] = sum; __syncthreads();
    for (int s = 128; s > 0; s >>= 1) { if (tid < s) red[tid] += red[tid + s]; __syncthreads(); }
    float inv = 1.f / red[0];
    for (int i = tid; i < VV; i += 256) out[(size_t)rr * VV + i] = expf(L[i] - m) * inv;
}

extern "C" void kernel_launch(void* const* d_in, const int* in_sizes, int n_in,
                              void* d_out, int out_size, void* d_ws, size_t ws_size,
                              hipStream_t stream) {
    const int*   x    = (const int*)  d_in[0];
    const float* tab  = (const float*)d_in[1];
    const float* Wx0  = (const float*)d_in[2];
    const float* Wh0  = (const float*)d_in[3];
    const float* b0   = (const float*)d_in[4];
    const float* Wx1  = (const float*)d_in[5];
    const float* Wh1  = (const float*)d_in[6];
    const float* b1   = (const float*)d_in[7];
    const float* Wout = (const float*)d_in[8];
    const float* bout = (const float*)d_in[9];
    float* out = (float*)d_out;

    // ---- workspace layout (ushort units); all segments 16B-aligned ----
    unsigned short* ws    = (unsigned short*)d_ws;
    unsigned short* embA  = ws;                    // 16,777,216
    unsigned short* wx0p  = embA  + 16777216;      //  2,097,152
    unsigned short* wh0p  = wx0p  + 2097152;       //  4,194,304
    unsigned short* wx1p  = wh0p  + 4194304;       //  4,194,304
    unsigned short* wh1p  = wx1p  + 4194304;       //  4,194,304
    unsigned short* woutp = wh1p  + 4194304;       // 32,768,000
    unsigned short* x4s   = woutp + 32768000;      // 134,217,728 (reused by both layers)
    unsigned short* h1A   = x4s   + 134217728;     // 33,554,432
    unsigned short* hb0   = h1A   + 33554432;      // 65,536  (layer 0)
    unsigned short* hb1   = hb0   + 65536;         // 65,536
    unsigned short* hb2   = hb1   + 65536;         // 65,536  (layer 1)
    unsigned short* hb3   = hb2   + 65536;         // 65,536
    float* logits = (float*)(hb3 + 65536);         // 2,048,000 f32
    unsigned int* flags = (unsigned int*)(logits + 2048000);  // 8192 u32 (2 layers x 2 halves x 128 x 16)
    // total ~472 MB

    // ---- weight packing ----
    pack_b <<<256 * 16, 64, 0, stream>>>(Wx0, wx0p, 16, GG);
    pack_wh<<<8192, 64, 0, stream>>>(Wh0, wh0p);
    pack_b <<<256 * 32, 64, 0, stream>>>(Wx1, wx1p, 32, GG);
    pack_wh<<<8192, 64, 0, stream>>>(Wh1, wh1p);
    pack_b <<<2000 * 32, 64, 0, stream>>>(Wout, woutp, 32, VV);

    // ---- h0 + flag init ----
    zero_init<<<64, 256, 0, stream>>>(hb0, hb2, flags);

    // ---- embedding + layer-0 input projection ----
    embed_pack<<<32768, 64, 0, stream>>>(x, tab, embA);
    gemm_bias<1><<<dim3(GG / 64, 32768 / 64), 256, 0, stream>>>(embA, wx0p, b0, x4s, GG, EE / 32);

    // ---- layer 0 recurrence (persistent cooperative) ----
    {
        const unsigned short* a0 = x4s; const unsigned short* a1 = wh0p;
        unsigned short *a2 = hb0, *a3 = hb1, *a4 = h1A;
        unsigned int* a5 = flags;
        void* args[] = {&a0, &a1, &a2, &a3, &a4, &a5};
        hipLaunchCooperativeKernel((const void*)lstm_layer, dim3(256), dim3(256),
                                   args, 0, stream);
    }

    // ---- layer-1 input projection + recurrence ----
    gemm_bias<1><<<dim3(GG / 64, 32768 / 64), 256, 0, stream>>>(h1A, wx1p, b1, x4s, GG, HH / 32);
    {
        const unsigned short* a0 = x4s; const unsigned short* a1 = wh1p;
        unsigned short *a2 = hb2, *a3 = hb3, *a4 = nullptr;
        unsigned int* a5 = flags + 4096;
        void* args[] = {&a0, &a1, &a2, &a3, &a4, &a5};
        hipLaunchCooperativeKernel((const void*)lstm_layer, dim3(256), dim3(256),
                                   args, 0, stream);
    }
    // t=511 (odd) writes hb2

    // ---- logits (last timestep) + softmax ----
    gemm_bias<0><<<dim3(VV / 64, 1), 256, 0, stream>>>(hb2, woutp, bout, logits, VV, HH / 32);
    softmax_rows<<<64, 256, 0, stream>>>(logits, out);
}